// Round 12
// baseline (237.257 us; speedup 1.0000x reference)
//
#include <hip/hip_runtime.h>

#define B 4
#define N 1024
#define K 100
#define F 42
#define H 64

#define PAIRS (K * F)          // 4200
#define MF4   (PAIRS * 3 / 4)  // 3150 f32x4 of dfeat per atom
#define QP    (PAIRS / 4)      // 1050 quad-pairs per atom
#define PW    68               // padded W row stride
#define GRID  1024             // exactly 4 blocks/CU * 256 CUs -> all co-resident
#define APB   4                // atoms per block (1 per wave in phase 1)

typedef float f32x4 __attribute__((ext_vector_type(4)));

__device__ __forceinline__ float rl(float v, int l) {
    return __int_as_float(__builtin_amdgcn_readlane(__float_as_int(v), l));
}

// ---------------------------------------------------------------------------
// Single fused kernel.
// Phase 1 (MLP): wave wv handles atom 4*bid+wv; lane = hidden unit; weights
//   in LDS; activation broadcasts via readlane (full-exec only — v11-proven).
// Device-wide barrier: counter in d_ws, zeroed by hipMemsetAsync each call;
//   release fence -> agent-scope atomicAdd -> spin -> acquire fence.
//   Co-residency guaranteed: launch_bounds(256,4) (VGPR<=128) + 36.5 KB LDS
//   => exactly 4 blocks/CU => 1024 blocks resident.
// Phase 2: blocks 0..3 also compute Etot (fixed-order); every block then
//   streams force for its 4 atoms (R9-proven body, dwordx4 dfeat loads).
// ---------------------------------------------------------------------------
__global__ __launch_bounds__(256, 4) void fused_kernel(
    const float* __restrict__ image, const float* __restrict__ dfeat,
    const int* __restrict__ neighbor,
    const float* __restrict__ W1, const float* __restrict__ b1,
    const float* __restrict__ W2, const float* __restrict__ b2,
    const float* __restrict__ W3, const float* __restrict__ b3,
    float* __restrict__ Etot, float* __restrict__ Ei,
    float* __restrict__ force, float* __restrict__ dE,
    unsigned* __restrict__ bar)
{
    __shared__ __align__(16) float W1s[H][PW];   // rows >= F zero-filled
    __shared__ __align__(16) float W2s[H][PW];
    __shared__ int   nshAll[APB * K];
    __shared__ float red[4][3];

    const int tid  = threadIdx.x;
    const int lane = tid & 63;
    const int wv   = tid >> 6;
    const int bid  = blockIdx.x;

    // ---- phase 1: staging ----
    for (int idx = tid; idx < H * H; idx += 256) {
        const int r = idx >> 6, c = idx & 63;
        W1s[r][c] = (r < F) ? W1[idx] : 0.0f;
        W2s[r][c] = W2[idx];
    }
    for (int idx = tid; idx < APB * K; idx += 256)
        nshAll[idx] = neighbor[(size_t)bid * (APB * K) + idx];
    __syncthreads();

    // ---- phase 1: MLP fwd + input grad, atom = 4*bid + wv ----
    const int atom = bid * APB + wv;
    const float x = (lane < F) ? image[(size_t)atom * F + lane] : 0.0f;

    float acc = b1[lane];
    #pragma unroll
    for (int f = 0; f < F; ++f)
        acc = fmaf(rl(x, f), W1s[f][lane], acc);
    const float h1 = tanhf(acc);

    float a2 = b2[lane];
    #pragma unroll
    for (int j = 0; j < H; ++j)
        a2 = fmaf(rl(h1, j), W2s[j][lane], a2);
    const float h2 = tanhf(a2);

    const float w3 = W3[lane];
    {
        float t = h2 * w3;
        #pragma unroll
        for (int off = 32; off > 0; off >>= 1) t += __shfl_down(t, off);
        if (lane == 0) Ei[atom] = t + b3[0];
    }
    const float g2 = w3 * (1.0f - h2 * h2);

    float s = 0.0f;
    #pragma unroll
    for (int ic = 0; ic < H / 4; ++ic) {
        const f32x4 wr = *(const f32x4*)&W2s[lane][4 * ic];
        s = fmaf(wr.x, rl(g2, 4 * ic + 0), s);
        s = fmaf(wr.y, rl(g2, 4 * ic + 1), s);
        s = fmaf(wr.z, rl(g2, 4 * ic + 2), s);
        s = fmaf(wr.w, rl(g2, 4 * ic + 3), s);
    }
    const float g1 = s * (1.0f - h1 * h1);

    float dx = 0.0f;   // all 64 lanes compute (W1s rows >= F are zero)
    #pragma unroll
    for (int ic = 0; ic < H / 4; ++ic) {
        const f32x4 wr = *(const f32x4*)&W1s[lane][4 * ic];
        dx = fmaf(wr.x, rl(g1, 4 * ic + 0), dx);
        dx = fmaf(wr.y, rl(g1, 4 * ic + 1), dx);
        dx = fmaf(wr.z, rl(g1, 4 * ic + 2), dx);
        dx = fmaf(wr.w, rl(g1, 4 * ic + 3), dx);
    }
    if (lane < F) dE[(size_t)atom * F + lane] = dx;

    // ---- device-wide barrier ----
    __threadfence();                       // release dE/Ei device-wide
    __syncthreads();                       // whole block arrived
    if (tid == 0) {
        __hip_atomic_fetch_add(bar, 1u, __ATOMIC_ACQ_REL, __HIP_MEMORY_SCOPE_AGENT);
        while (__hip_atomic_load(bar, __ATOMIC_ACQUIRE, __HIP_MEMORY_SCOPE_AGENT) < GRID)
            __builtin_amdgcn_s_sleep(2);
    }
    __syncthreads();
    __threadfence();                       // acquire: no stale L1/L2 reads

    // ---- phase 2a: Etot (blocks 0..3, fixed-order deterministic sum) ----
    if (bid < B) {
        float s2 = 0.0f;
        for (int i = tid; i < N; i += 256) s2 += Ei[bid * N + i];
        #pragma unroll
        for (int off = 32; off > 0; off >>= 1) s2 += __shfl_down(s2, off);
        if (lane == 0) red[wv][0] = s2;
        __syncthreads();
        if (tid == 0)
            Etot[bid] = (red[0][0] + red[1][0]) + (red[2][0] + red[3][0]);
        __syncthreads();                   // red reused below
    }

    // ---- phase 2b: force for atoms 4*bid .. 4*bid+3 (R9 body) ----
    #pragma unroll 1
    for (int t = 0; t < APB; ++t) {
        const int bn = bid * APB + t;
        const int b  = bn >> 10;           // N = 1024
        const f32x4* df4 = (const f32x4*)dfeat + (size_t)bn * MF4;
        const float* dEb = dE + (size_t)b * (N * F);
        const int*   nsh = &nshAll[t * K];

        float fx = 0.0f, fy = 0.0f, fz = 0.0f;

        #pragma unroll 1
        for (int it = 0; it < 4; ++it) {   // quad-pairs 0..1023
            const int p4 = it * 256 + tid;
            const int p  = 4 * p4;
            const f32x4 d0 = df4[3 * p4 + 0];
            const f32x4 d1 = df4[3 * p4 + 1];
            const f32x4 d2 = df4[3 * p4 + 2];
            float e[4];
            #pragma unroll
            for (int q = 0; q < 4; ++q) {
                const int pp = p + q;
                const int k  = pp / F;
                const int f  = pp - k * F;
                const int nb = nsh[k];
                e[q] = (nb > 0) ? dEb[(nb - 1) * F + f] : 0.0f;
            }
            fx = fmaf(e[0], d0.x, fx); fy = fmaf(e[0], d0.y, fy); fz = fmaf(e[0], d0.z, fz);
            fx = fmaf(e[1], d0.w, fx); fy = fmaf(e[1], d1.x, fy); fz = fmaf(e[1], d1.y, fz);
            fx = fmaf(e[2], d1.z, fx); fy = fmaf(e[2], d1.w, fy); fz = fmaf(e[2], d2.x, fz);
            fx = fmaf(e[3], d2.y, fx); fy = fmaf(e[3], d2.z, fy); fz = fmaf(e[3], d2.w, fz);
        }
        if (tid < QP - 1024) {             // tail: quad-pairs 1024..1049
            const int p4 = 1024 + tid;
            const int p  = 4 * p4;
            const f32x4 d0 = df4[3 * p4 + 0];
            const f32x4 d1 = df4[3 * p4 + 1];
            const f32x4 d2 = df4[3 * p4 + 2];
            float e[4];
            #pragma unroll
            for (int q = 0; q < 4; ++q) {
                const int pp = p + q;
                const int k  = pp / F;
                const int f  = pp - k * F;
                const int nb = nsh[k];
                e[q] = (nb > 0) ? dEb[(nb - 1) * F + f] : 0.0f;
            }
            fx = fmaf(e[0], d0.x, fx); fy = fmaf(e[0], d0.y, fy); fz = fmaf(e[0], d0.z, fz);
            fx = fmaf(e[1], d0.w, fx); fy = fmaf(e[1], d1.x, fy); fz = fmaf(e[1], d1.y, fz);
            fx = fmaf(e[2], d1.z, fx); fy = fmaf(e[2], d1.w, fy); fz = fmaf(e[2], d2.x, fz);
            fx = fmaf(e[3], d2.y, fx); fy = fmaf(e[3], d2.z, fy); fz = fmaf(e[3], d2.w, fz);
        }

        #pragma unroll
        for (int off = 32; off > 0; off >>= 1) {
            fx += __shfl_down(fx, off);
            fy += __shfl_down(fy, off);
            fz += __shfl_down(fz, off);
        }
        if (lane == 0) { red[wv][0] = fx; red[wv][1] = fy; red[wv][2] = fz; }
        __syncthreads();
        if (tid == 0) {
            force[bn * 3 + 0] = (red[0][0] + red[1][0]) + (red[2][0] + red[3][0]);
            force[bn * 3 + 1] = (red[0][1] + red[1][1]) + (red[2][1] + red[3][1]);
            force[bn * 3 + 2] = (red[0][2] + red[1][2]) + (red[2][2] + red[3][2]);
        }
        __syncthreads();                   // red reused next t
    }
}

extern "C" void kernel_launch(void* const* d_in, const int* in_sizes, int n_in,
                              void* d_out, int out_size, void* d_ws, size_t ws_size,
                              hipStream_t stream)
{
    const float* image    = (const float*)d_in[0];
    const float* dfeat    = (const float*)d_in[1];
    const int*   neighbor = (const int*)d_in[2];
    // d_in[3] Egroup_weight, d_in[4] divider: unused by the reference outputs
    const float* W1 = (const float*)d_in[5];
    const float* b1 = (const float*)d_in[6];
    const float* W2 = (const float*)d_in[7];
    const float* b2 = (const float*)d_in[8];
    const float* W3 = (const float*)d_in[9];
    const float* b3 = (const float*)d_in[10];

    float* out   = (float*)d_out;
    float* Etot  = out;                                  // [B]
    float* Ei    = out + B;                              // [B,N]
    float* Force = out + B + B * N;                      // [B,N,3]
    float* dE    = (float*)d_ws;                         // [B,N,F]
    unsigned* bar = (unsigned*)((char*)d_ws + (size_t)B * N * F * sizeof(float));

    hipMemsetAsync(bar, 0, sizeof(unsigned), stream);    // reset barrier each call
    fused_kernel<<<GRID, 256, 0, stream>>>(image, dfeat, neighbor,
                                           W1, b1, W2, b2, W3, b3,
                                           Etot, Ei, Force, dE, bar);
}

// Round 13
// 44.778 us; speedup vs baseline: 5.2985x; 5.2985x over previous
//
#include <hip/hip_runtime.h>

#define B 4
#define N 1024
#define K 100
#define F 42
#define H 64

#define PAIRS (K * F)          // 4200
#define MF4   (PAIRS * 3 / 4)  // 3150 f32x4 of dfeat per atom
#define QP    (PAIRS / 4)      // 1050 quad-pairs per atom

#define APW 2                  // mlp: atoms per wave  (was 4)
#define NWV 8                  // mlp: waves per block (was 4) -> 2 waves/SIMD
#define APB (APW * NWV)        // 16 atoms/block -> grid 256 (1 block/CU)
#define BT  (NWV * 64)         // 512 threads
#define PW  68
#define PX  44

typedef float f32x4 __attribute__((ext_vector_type(4)));

// ---------------------------------------------------------------------------
// Kernel 1 (v13 = v7 reshaped): MLP fwd + input grad. lane = hidden unit,
// wave = 2 atoms, 8 waves/block (2/SIMD -> latency hiding), W in LDS,
// b128 LDS traffic, wave-local exchanges. Math identical to v7 (proven).
// ---------------------------------------------------------------------------
__global__ __launch_bounds__(BT) void mlp_kernel(
    const float* __restrict__ image,
    const float* __restrict__ W1, const float* __restrict__ b1,
    const float* __restrict__ W2, const float* __restrict__ b2,
    const float* __restrict__ W3, const float* __restrict__ b3,
    float* __restrict__ Ei, float* __restrict__ dE)
{
    __shared__ __align__(16) float W1s[F][PW];
    __shared__ __align__(16) float W2s[H][PW];
    __shared__ __align__(16) float xsh[APB][PX];
    __shared__ __align__(16) float h1sh[NWV][APW][H];
    __shared__ __align__(16) float g2sh[NWV][APW][H];
    __shared__ __align__(16) float g1sh[NWV][APW][H];

    const int tid  = threadIdx.x;
    const int lane = tid & 63;
    const int wv   = tid >> 6;          // 0..7
    const int a0   = blockIdx.x * APB;
    const int aw   = a0 + wv * APW;

    for (int idx = tid; idx < F * H; idx += BT)
        W1s[idx >> 6][idx & 63] = W1[idx];
    for (int idx = tid; idx < H * H; idx += BT)
        W2s[idx >> 6][idx & 63] = W2[idx];
    for (int idx = tid; idx < APB * F; idx += BT) {
        const int a = idx / F, f = idx - a * F;
        xsh[a][f] = image[(size_t)a0 * F + idx];
    }
    __syncthreads();

    float acc[APW];
    {
        const float bb = b1[lane];
        #pragma unroll
        for (int a = 0; a < APW; ++a) acc[a] = bb;
    }
    #pragma unroll
    for (int fc = 0; fc < 10; ++fc) {
        float wv4[4];
        #pragma unroll
        for (int t = 0; t < 4; ++t) wv4[t] = W1s[4 * fc + t][lane];
        #pragma unroll
        for (int a = 0; a < APW; ++a) {
            const f32x4 xv = *(const f32x4*)&xsh[wv * APW + a][4 * fc];
            #pragma unroll
            for (int t = 0; t < 4; ++t) acc[a] = fmaf(xv[t], wv4[t], acc[a]);
        }
    }
    #pragma unroll
    for (int f = 40; f < F; ++f) {
        const float w = W1s[f][lane];
        #pragma unroll
        for (int a = 0; a < APW; ++a) acc[a] = fmaf(xsh[wv * APW + a][f], w, acc[a]);
    }
    float h1l[APW];
    #pragma unroll
    for (int a = 0; a < APW; ++a) {
        h1l[a] = tanhf(acc[a]);
        h1sh[wv][a][lane] = h1l[a];
    }
    __builtin_amdgcn_wave_barrier();

    {
        const float bb = b2[lane];
        #pragma unroll
        for (int a = 0; a < APW; ++a) acc[a] = bb;
    }
    #pragma unroll
    for (int jc = 0; jc < H / 4; ++jc) {
        float wv4[4];
        #pragma unroll
        for (int t = 0; t < 4; ++t) wv4[t] = W2s[4 * jc + t][lane];
        #pragma unroll
        for (int a = 0; a < APW; ++a) {
            const f32x4 hv = *(const f32x4*)&h1sh[wv][a][4 * jc];
            #pragma unroll
            for (int t = 0; t < 4; ++t) acc[a] = fmaf(hv[t], wv4[t], acc[a]);
        }
    }
    const float w3    = W3[lane];
    const float bias3 = b3[0];
    #pragma unroll
    for (int a = 0; a < APW; ++a) {
        const float h2 = tanhf(acc[a]);
        g2sh[wv][a][lane] = w3 * (1.0f - h2 * h2);
        float t = h2 * w3;
        #pragma unroll
        for (int off = 32; off > 0; off >>= 1) t += __shfl_down(t, off);
        if (lane == 0) Ei[aw + a] = t + bias3;
    }
    __builtin_amdgcn_wave_barrier();

    float s[APW];
    #pragma unroll
    for (int a = 0; a < APW; ++a) s[a] = 0.0f;
    #pragma unroll
    for (int ic = 0; ic < H / 4; ++ic) {
        const f32x4 wr = *(const f32x4*)&W2s[lane][4 * ic];
        #pragma unroll
        for (int a = 0; a < APW; ++a) {
            const f32x4 gv = *(const f32x4*)&g2sh[wv][a][4 * ic];
            #pragma unroll
            for (int t = 0; t < 4; ++t) s[a] = fmaf(wr[t], gv[t], s[a]);
        }
    }
    #pragma unroll
    for (int a = 0; a < APW; ++a)
        g1sh[wv][a][lane] = s[a] * (1.0f - h1l[a] * h1l[a]);
    __builtin_amdgcn_wave_barrier();

    if (lane < F) {
        float dx[APW];
        #pragma unroll
        for (int a = 0; a < APW; ++a) dx[a] = 0.0f;
        #pragma unroll
        for (int ic = 0; ic < H / 4; ++ic) {
            const f32x4 wr = *(const f32x4*)&W1s[lane][4 * ic];
            #pragma unroll
            for (int a = 0; a < APW; ++a) {
                const f32x4 gv = *(const f32x4*)&g1sh[wv][a][4 * ic];
                #pragma unroll
                for (int t = 0; t < 4; ++t) dx[a] = fmaf(wr[t], gv[t], dx[a]);
            }
        }
        #pragma unroll
        for (int a = 0; a < APW; ++a)
            dE[(size_t)(aw + a) * F + lane] = dx[a];
    }
}

// ---------------------------------------------------------------------------
// Kernel 2 (R9, byte-identical — measured at ~6.6 TB/s effective, above the
// 6.3 TB/s copy ceiling thanks to partial L3 residency): Force + Etot tails.
// ---------------------------------------------------------------------------
__global__ __launch_bounds__(256) void force_kernel(
    const float* __restrict__ dE, const float* __restrict__ dfeat,
    const int* __restrict__ neighbor, const float* __restrict__ Ei,
    float* __restrict__ force, float* __restrict__ Etot)
{
    __shared__ int   nsh[K];
    __shared__ float red[4][3];

    const int tid  = threadIdx.x;
    const int bid  = blockIdx.x;
    const int lane = tid & 63, wave = tid >> 6;

    if (bid >= B * N) {                    // ---- Etot tail blocks ----
        const int b = bid - B * N;
        float s = 0.0f;
        for (int i = tid; i < N; i += 256) s += Ei[b * N + i];
        #pragma unroll
        for (int off = 32; off > 0; off >>= 1) s += __shfl_down(s, off);
        if (lane == 0) red[wave][0] = s;
        __syncthreads();
        if (tid == 0)
            Etot[b] = (red[0][0] + red[1][0]) + (red[2][0] + red[3][0]);
        return;
    }

    const int bn = bid;
    const int b  = bn >> 10;               // N = 1024

    if (tid < K) nsh[tid] = neighbor[bn * K + tid];
    __syncthreads();

    const f32x4* df4 = (const f32x4*)dfeat + (size_t)bn * MF4;
    const float* dEb = dE + (size_t)b * (N * F);

    float fx = 0.0f, fy = 0.0f, fz = 0.0f;

    #pragma unroll 1
    for (int it = 0; it < 4; ++it) {       // full iters: quad-pairs 0..1023
        const int p4 = it * 256 + tid;
        const int p  = 4 * p4;
        const f32x4 d0 = df4[3 * p4 + 0];
        const f32x4 d1 = df4[3 * p4 + 1];
        const f32x4 d2 = df4[3 * p4 + 2];
        float e[4];
        #pragma unroll
        for (int q = 0; q < 4; ++q) {
            const int pp = p + q;
            const int k  = pp / F;
            const int f  = pp - k * F;
            const int nb = nsh[k];
            e[q] = (nb > 0) ? dEb[(nb - 1) * F + f] : 0.0f;
        }
        fx = fmaf(e[0], d0.x, fx); fy = fmaf(e[0], d0.y, fy); fz = fmaf(e[0], d0.z, fz);
        fx = fmaf(e[1], d0.w, fx); fy = fmaf(e[1], d1.x, fy); fz = fmaf(e[1], d1.y, fz);
        fx = fmaf(e[2], d1.z, fx); fy = fmaf(e[2], d1.w, fy); fz = fmaf(e[2], d2.x, fz);
        fx = fmaf(e[3], d2.y, fx); fy = fmaf(e[3], d2.z, fy); fz = fmaf(e[3], d2.w, fz);
    }
    if (tid < QP - 1024) {                 // tail: quad-pairs 1024..1049
        const int p4 = 1024 + tid;
        const int p  = 4 * p4;
        const f32x4 d0 = df4[3 * p4 + 0];
        const f32x4 d1 = df4[3 * p4 + 1];
        const f32x4 d2 = df4[3 * p4 + 2];
        float e[4];
        #pragma unroll
        for (int q = 0; q < 4; ++q) {
            const int pp = p + q;
            const int k  = pp / F;
            const int f  = pp - k * F;
            const int nb = nsh[k];
            e[q] = (nb > 0) ? dEb[(nb - 1) * F + f] : 0.0f;
        }
        fx = fmaf(e[0], d0.x, fx); fy = fmaf(e[0], d0.y, fy); fz = fmaf(e[0], d0.z, fz);
        fx = fmaf(e[1], d0.w, fx); fy = fmaf(e[1], d1.x, fy); fz = fmaf(e[1], d1.y, fz);
        fx = fmaf(e[2], d1.z, fx); fy = fmaf(e[2], d1.w, fy); fz = fmaf(e[2], d2.x, fz);
        fx = fmaf(e[3], d2.y, fx); fy = fmaf(e[3], d2.z, fy); fz = fmaf(e[3], d2.w, fz);
    }

    #pragma unroll
    for (int off = 32; off > 0; off >>= 1) {
        fx += __shfl_down(fx, off);
        fy += __shfl_down(fy, off);
        fz += __shfl_down(fz, off);
    }
    if (lane == 0) { red[wave][0] = fx; red[wave][1] = fy; red[wave][2] = fz; }
    __syncthreads();
    if (tid == 0) {
        force[bn * 3 + 0] = (red[0][0] + red[1][0]) + (red[2][0] + red[3][0]);
        force[bn * 3 + 1] = (red[0][1] + red[1][1]) + (red[2][1] + red[3][1]);
        force[bn * 3 + 2] = (red[0][2] + red[1][2]) + (red[2][2] + red[3][2]);
    }
}

extern "C" void kernel_launch(void* const* d_in, const int* in_sizes, int n_in,
                              void* d_out, int out_size, void* d_ws, size_t ws_size,
                              hipStream_t stream)
{
    const float* image    = (const float*)d_in[0];
    const float* dfeat    = (const float*)d_in[1];
    const int*   neighbor = (const int*)d_in[2];
    // d_in[3] Egroup_weight, d_in[4] divider: unused by the reference outputs
    const float* W1 = (const float*)d_in[5];
    const float* b1 = (const float*)d_in[6];
    const float* W2 = (const float*)d_in[7];
    const float* b2 = (const float*)d_in[8];
    const float* W3 = (const float*)d_in[9];
    const float* b3 = (const float*)d_in[10];

    float* out   = (float*)d_out;
    float* Etot  = out;                 // [B]
    float* Ei    = out + B;             // [B,N]
    float* Force = out + B + B * N;     // [B,N,3]
    float* dE    = (float*)d_ws;        // [B,N,F]

    mlp_kernel<<<(B * N) / APB, BT, 0, stream>>>(image, W1, b1, W2, b2, W3, b3, Ei, dE);
    force_kernel<<<B * N + B, 256, 0, stream>>>(dE, dfeat, neighbor, Ei, Force, Etot);
}